// Round 5
// baseline (533.330 us; speedup 1.0000x reference)
//
#include <hip/hip_runtime.h>
#include <math.h>

#define B_   16
#define L_   256
#define V_   50000
#define NV_  50100
#define E_   128
#define H_   128
#define G4_  512
#define CHUNK_  1566   // ceil(50100/32)
#define CHUNKP_ 6263   // ceil(50100/8)

typedef float f32x4 __attribute__((ext_vector_type(4)));
typedef float f32x2 __attribute__((ext_vector_type(2)));

__device__ __forceinline__ float sigm(float x){ return 1.0f/(1.0f+__expf(-x)); }
__device__ __forceinline__ float tanh_fast(float x){
  x = fminf(15.0f, fmaxf(-15.0f, x));
  float t = __expf(2.0f*x);
  return (t-1.0f)/(t+1.0f);
}

// ---------------- K1: encoder xg = emb[tok] @ W_ih^T + b ----------------
__global__ __launch_bounds__(512) void enc_xg_kernel(
    const int* __restrict__ tok, const float* __restrict__ emb,
    const float* __restrict__ Wih, const float* __restrict__ bias,
    float* __restrict__ xg)
{
  __shared__ __align__(16) float sx[16*128];
  int r0 = blockIdx.x*16;
  int t = threadIdx.x;
  for (int i=t; i<16*128; i+=512){
    int r=i>>7, e=i&127;
    sx[i] = emb[(size_t)tok[r0+r]*E_ + e];
  }
  __syncthreads();
  int g = t;
  float acc[16];
  #pragma unroll
  for (int r=0;r<16;r++) acc[r]=0.f;
  const f32x4* wr = (const f32x4*)(Wih + (size_t)g*E_);
  #pragma unroll 2
  for (int i=0;i<32;i++){
    f32x4 w = wr[i];
    #pragma unroll
    for (int r=0;r<16;r++){
      f32x4 x = ((const f32x4*)(sx + r*128))[i];
      acc[r] += w.x*x.x + w.y*x.y + w.z*x.z + w.w*x.w;
    }
  }
  float bg = bias[g];
  #pragma unroll
  for (int r=0;r<16;r++) xg[(size_t)(r0+r)*G4_ + g] = acc[r] + bg;
}

// ---------------- K2: encoder LSTM recurrence ----------------
// 16 blocks (one per batch), 256 threads (4 waves = 1 wave/SIMD).
// Thread t owns TWO gate rows: g0=t (i/f -> sigmoid), g1=t+256 (gg/o).
// __launch_bounds__(256,1) -> 512-VGPR budget; W pressure = 256 regs for
// both rows + ~60 misc, comfortably resident -> kills the 256KB/step L2
// reload that R2-R4 counters proved was the bottleneck (38% VALUBusy on
// active CUs = reload addressing; 1920cy/step = 256KB / ~135B/cy L2 BW).
__global__ __launch_bounds__(256, 1) void enc_lstm_kernel(
    const float* __restrict__ xg, const float* __restrict__ Whh,
    float* __restrict__ enc_out)
{
  int b = blockIdx.x;
  int t = threadIdx.x;       // 0..255
  int g0 = t;
  int g1 = t + 256;

  f32x2 wa[64], wb[64];
  {
    const f32x4* wr0 = (const f32x4*)(Whh + (size_t)g0*H_);
    const f32x4* wr1 = (const f32x4*)(Whh + (size_t)g1*H_);
    #pragma unroll
    for (int k=0;k<32;k++){ f32x4 v=wr0[k]; wa[2*k]=v.xy; wa[2*k+1]=v.zw; }
    #pragma unroll
    for (int k=0;k<32;k++){ f32x4 v=wr1[k]; wb[2*k]=v.xy; wb[2*k+1]=v.zw; }
  }
  #pragma unroll
  for (int k=0;k<64;k++){ asm volatile("" : "+v"(wa[k])); asm volatile("" : "+v"(wb[k])); }

  __shared__ __align__(16) float sh_h[128];
  __shared__ float sh_g[512];
  if (t<128) sh_h[t]=0.f;
  float c = 0.f;
  const float* xgb = xg + (size_t)b*L_*G4_;
  float* eob = enc_out + (size_t)b*L_*H_;
  __syncthreads();

  const f32x4* sh4 = (const f32x4*)sh_h;
  bool g1_tanh = (t < 128);   // wave-uniform: waves 0-1 own gg rows, 2-3 own o rows

  // prefetch depth 2 (step time ~600cy < HBM latency)
  float xc0 = xgb[g0],        xc1 = xgb[g1];
  float xn0 = xgb[G4_ + g0],  xn1 = xgb[G4_ + g1];

  for (int s=0;s<L_;s++){
    float xm0=0.f, xm1=0.f;
    if (s+2 < L_){ xm0 = xgb[(size_t)(s+2)*G4_ + g0]; xm1 = xgb[(size_t)(s+2)*G4_ + g1]; }

    f32x2 a0={xc0,0.f}, a1={0.f,0.f}, a2={0.f,0.f}, a3={0.f,0.f};
    f32x2 b0={xc1,0.f}, b1={0.f,0.f}, b2={0.f,0.f}, b3={0.f,0.f};
    #pragma unroll
    for (int k=0;k<32;k+=4){
      f32x4 h0=sh4[k], h1=sh4[k+1], h2v=sh4[k+2], h3=sh4[k+3];
      a0 += wa[2*k+0]*h0.xy;  a1 += wa[2*k+1]*h0.zw;
      b0 += wb[2*k+0]*h0.xy;  b1 += wb[2*k+1]*h0.zw;
      a2 += wa[2*k+2]*h1.xy;  a3 += wa[2*k+3]*h1.zw;
      b2 += wb[2*k+2]*h1.xy;  b3 += wb[2*k+3]*h1.zw;
      a0 += wa[2*k+4]*h2v.xy; a1 += wa[2*k+5]*h2v.zw;
      b0 += wb[2*k+4]*h2v.xy; b1 += wb[2*k+5]*h2v.zw;
      a2 += wa[2*k+6]*h3.xy;  a3 += wa[2*k+7]*h3.zw;
      b2 += wb[2*k+6]*h3.xy;  b3 += wb[2*k+7]*h3.zw;
    }
    f32x2 as=(a0+a1)+(a2+a3);
    f32x2 bs=(b0+b1)+(b2+b3);
    float acc0 = as.x+as.y;
    float acc1 = bs.x+bs.y;
    sh_g[g0] = sigm(acc0);                                   // i or f gate
    sh_g[g1] = g1_tanh ? tanh_fast(acc1) : sigm(acc1);       // gg or o gate
    __syncthreads();
    if (t < 128){
      c = sh_g[128+t]*c + sh_g[t]*sh_g[256+t];
      float h = sh_g[384+t]*tanh_fast(c);
      sh_h[t] = h;
      eob[(size_t)s*H_ + t] = h;
    }
    __syncthreads();
    xc0=xn0; xc1=xn1; xn0=xm0; xn1=xm1;
    #pragma unroll
    for (int k=0;k<64;k++){ asm volatile("" : "+v"(wa[k])); asm volatile("" : "+v"(wb[k])); }
  }
}

// ---------------- fused: [blocks 0-15] mid chain  /  [blocks 16-31] token agg ----------------
__global__ __launch_bounds__(512) void midagg_kernel(
    const int* __restrict__ src, const int* __restrict__ prev,
    const float* __restrict__ enc_out, const float* __restrict__ cW,
    const float* __restrict__ dstate, const float* __restrict__ emb,
    const float* __restrict__ dWih, const float* __restrict__ db,
    const float* __restrict__ aW, const float* __restrict__ oW,
    const float* __restrict__ ob, float* __restrict__ attn_out,
    const int* __restrict__ stw, float* __restrict__ agg,
    int* __restrict__ replist, int* __restrict__ repcnt)
{
  int t=threadIdx.x;
  if (blockIdx.x >= 16){
    // ======== copy_agg path (first-occurrence aggregation) ========
    int b = blockIdx.x - 16;
    __shared__ int stok[256];
    __shared__ int scnt;
    if (t<256) stok[t] = stw[b*L_+t];
    if (t==0) scnt=0;
    __syncthreads();
    if (t<256){
      int tok = stok[t];
      int first=0;
      while (stok[first]!=tok) first++;
      if (first==t){
        int myidx = atomicAdd(&scnt,1);
        f32x4 acc[32];
        #pragma unroll
        for (int i=0;i<32;i++) acc[i]=(f32x4){0.f,0.f,0.f,0.f};
        for (int l2=t; l2<L_; l2++){
          if (stok[l2]==tok){
            const f32x4* e=(const f32x4*)(enc_out + ((size_t)b*L_+l2)*H_);
            #pragma unroll
            for (int i=0;i<32;i++) acc[i]+=e[i];
          }
        }
        f32x4* dst=(f32x4*)(agg + ((size_t)b*L_+t)*H_);
        #pragma unroll
        for (int i=0;i<32;i++) dst[i]=acc[i];
        replist[b*L_+myidx]=t;
      }
    }
    __syncthreads();
    if (t==0) repcnt[b]=scnt;
    return;
  }

  // ======== mid path: copy scores + copy softmax/state + dec step + attention ========
  int b=blockIdx.x;
  __shared__ float s_scopy[256];
  __shared__ int   mlist[256];
  __shared__ int   mcnt;
  __shared__ __align__(16) float se[128];
  __shared__ float sw[256];
  __shared__ float spart[512];
  __shared__ float sred[4];
  __shared__ __align__(16) float sin_[256];
  __shared__ float sg[512];
  __shared__ __align__(16) float sr[128];
  __shared__ __align__(16) float sq[128];
  __shared__ float sc[256];
  __shared__ __align__(16) float sctx[128];

  if (t==0) mcnt=0;
  __syncthreads();
  if (t<256){
    s_scopy[t]=0.f;
    if (src[b*L_+t]==prev[b]){ int i=atomicAdd(&mcnt,1); mlist[i]=t; }
  }
  __syncthreads();
  for (int mi=0; mi<mcnt; mi++){
    int l = mlist[mi];
    if (t<128) se[t] = enc_out[((size_t)b*L_+l)*H_ + t];
    __syncthreads();
    if (t<128){
      const f32x4* wr = (const f32x4*)(cW + (size_t)t*H_);
      const f32x4* e4 = (const f32x4*)se;
      float acc=0.f;
      #pragma unroll
      for (int i=0;i<32;i++){
        f32x4 wv=wr[i], e=e4[i];
        acc += wv.x*e.x + wv.y*e.y + wv.z*e.z + wv.w*e.w;
      }
      float v = tanhf(acc)*dstate[b*H_+t];
      #pragma unroll
      for (int o=32;o;o>>=1) v += __shfl_down(v,o);
      if ((t&63)==0) sred[t>>6]=v;
    }
    __syncthreads();
    if (t==0) s_scopy[l]=sred[0]+sred[1];
    __syncthreads();
  }

  // softmax over copy scores
  float v = (t<256) ? s_scopy[t] : -INFINITY;
  {
    float m=v;
    #pragma unroll
    for (int o=32;o;o>>=1) m=fmaxf(m,__shfl_down(m,o));
    if (t<256 && (t&63)==0) sred[t>>6]=m;
  }
  __syncthreads();
  float m4 = fmaxf(fmaxf(sred[0],sred[1]),fmaxf(sred[2],sred[3]));
  __syncthreads();
  float e = (t<256) ? __expf(v-m4) : 0.f;
  {
    float z=e;
    #pragma unroll
    for (int o=32;o;o>>=1) z += __shfl_down(z,o);
    if (t<256 && (t&63)==0) sred[t>>6]=z;
  }
  __syncthreads();
  {
    float z4 = sred[0]+sred[1]+sred[2]+sred[3];
    if (t<256) sw[t] = e/z4;
  }
  __syncthreads();

  // copy_state
  {
    int ch=t>>7, h=t&127;
    float acc=0.f;
    const float* eb = enc_out + (size_t)b*L_*H_;
    for (int l=ch*64; l<ch*64+64; l++) acc += sw[l]*eb[(size_t)l*H_+h];
    spart[t]=acc;
  }
  __syncthreads();
  if (t<128){
    float cst = spart[t]+spart[128+t]+spart[256+t]+spart[384+t];
    sin_[128+t]=cst;
    sin_[t]=emb[(size_t)prev[b]*E_+t];
  }
  __syncthreads();

  // decoder single LSTM step (h0=c0=0)
  {
    const f32x4* wr=(const f32x4*)(dWih + (size_t)t*256);
    const f32x4* x4=(const f32x4*)sin_;
    f32x2 d0={db[t],0.f}, d1={0.f,0.f}, d2={0.f,0.f}, d3={0.f,0.f};
    #pragma unroll
    for (int k=0;k<64;k+=4){
      f32x4 xa=x4[k], xb=x4[k+1], xc=x4[k+2], xd=x4[k+3];
      f32x4 wva=wr[k], wvb=wr[k+1], wvc=wr[k+2], wvd=wr[k+3];
      d0 += wva.xy*xa.xy; d1 += wva.zw*xa.zw;
      d2 += wvb.xy*xb.xy; d3 += wvb.zw*xb.zw;
      d0 += wvc.xy*xc.xy; d1 += wvc.zw*xc.zw;
      d2 += wvd.xy*xd.xy; d3 += wvd.zw*xd.zw;
    }
    f32x2 dsm=(d0+d1)+(d2+d3);
    sg[t]=dsm.x+dsm.y;
  }
  __syncthreads();
  if (t<128){
    float iv=sg[t], gv=sg[256+t], ov=sg[384+t];
    float cc = sigm(iv)*tanhf(gv);
    sr[t] = sigm(ov)*tanhf(cc);
  }
  __syncthreads();

  // q = attn_W @ rnn
  if (t<128){
    const f32x4* wr=(const f32x4*)(aW + (size_t)t*H_);
    const f32x4* x4=(const f32x4*)sr;
    float acc=0.f;
    #pragma unroll
    for (int i=0;i<32;i++){
      f32x4 wv=wr[i], x=x4[i];
      acc += wv.x*x.x + wv.y*x.y + wv.z*x.z + wv.w*x.w;
    }
    sq[t]=acc;
  }
  __syncthreads();

  // scores + pad mask
  if (t<256){
    const f32x4* e4=(const f32x4*)(enc_out + ((size_t)b*L_+t)*H_);
    const f32x4* q4=(const f32x4*)sq;
    float acc=0.f;
    #pragma unroll
    for (int i=0;i<32;i++){
      f32x4 ev=e4[i], q=q4[i];
      acc += ev.x*q.x + ev.y*q.y + ev.z*q.z + ev.w*q.w;
    }
    if (src[b*L_+t]==0) acc=-INFINITY;
    sc[t]=acc;
  }
  __syncthreads();

  // attn softmax
  v = (t<256) ? sc[t] : -INFINITY;
  {
    float m=v;
    #pragma unroll
    for (int o=32;o;o>>=1) m=fmaxf(m,__shfl_down(m,o));
    if (t<256 && (t&63)==0) sred[t>>6]=m;
  }
  __syncthreads();
  m4 = fmaxf(fmaxf(sred[0],sred[1]),fmaxf(sred[2],sred[3]));
  __syncthreads();
  e = (t<256) ? __expf(v-m4) : 0.f;
  {
    float z=e;
    #pragma unroll
    for (int o=32;o;o>>=1) z += __shfl_down(z,o);
    if (t<256 && (t&63)==0) sred[t>>6]=z;
  }
  __syncthreads();
  {
    float z4 = sred[0]+sred[1]+sred[2]+sred[3];
    if (t<256) sc[t] = e/z4;
  }
  __syncthreads();

  // ctx
  {
    int ch=t>>7, h=t&127;
    float acc=0.f;
    const float* eb = enc_out + (size_t)b*L_*H_;
    for (int l=ch*64; l<ch*64+64; l++) acc += sc[l]*eb[(size_t)l*H_+h];
    spart[t]=acc;
  }
  __syncthreads();
  if (t<128) sctx[t] = spart[t]+spart[128+t]+spart[256+t]+spart[384+t];
  __syncthreads();

  // attn_out = tanh(out_W @ [rnn,ctx] + out_b)
  if (t<128){
    const f32x4* wr=(const f32x4*)(oW + (size_t)t*256);
    const f32x4* r4=(const f32x4*)sr;
    const f32x4* c4=(const f32x4*)sctx;
    float acc=ob[t];
    #pragma unroll
    for (int i=0;i<32;i++){
      f32x4 wv=wr[i], x=r4[i];
      acc += wv.x*x.x + wv.y*x.y + wv.z*x.z + wv.w*x.w;
    }
    #pragma unroll
    for (int i=0;i<32;i++){
      f32x4 wv=wr[32+i], x=c4[i];
      acc += wv.x*x.x + wv.y*x.y + wv.z*x.z + wv.w*x.w;
    }
    attn_out[b*H_+t]=tanhf(acc);
  }
}

// ---------------- K9: gen logits + masks -> total ----------------
__global__ __launch_bounds__(256) void gen_logits_kernel(
    const float* __restrict__ attn_out, const float* __restrict__ gW,
    const int* __restrict__ oovc, float* __restrict__ total)
{
  __shared__ float sa[B_*H_];
  __shared__ float sw[64*129];
  int t=threadIdx.x;
  int v0=blockIdx.x*64;
  for (int i=t;i<B_*H_;i+=256) sa[i]=attn_out[i];
  for (int i=t;i<64*32;i+=256){
    int r=i>>5, cc=i&31;
    if (v0+r<NV_){
      float4 wv = ((const float4*)(gW + (size_t)(v0+r)*H_))[cc];
      float* dst = sw + r*129 + cc*4;
      dst[0]=wv.x; dst[1]=wv.y; dst[2]=wv.z; dst[3]=wv.w;
    }
  }
  __syncthreads();
  int vl=t&63, bq=t>>6;
  int v=v0+vl;
  if (v>=NV_) return;
  float acc[4]={0.f,0.f,0.f,0.f};
  const float* wrow = sw + vl*129;
  #pragma unroll 8
  for (int h4=0; h4<32; h4++){
    float w0=wrow[h4*4+0], w1=wrow[h4*4+1], w2=wrow[h4*4+2], w3=wrow[h4*4+3];
    #pragma unroll
    for (int k=0;k<4;k++){
      float4 a = ((const float4*)(sa + (bq*4+k)*H_))[h4];
      acc[k] += w0*a.x + w1*a.y + w2*a.z + w3*a.w;
    }
  }
  #pragma unroll
  for (int k=0;k<4;k++){
    int b=bq*4+k;
    float o = (v==1 || v >= V_ + oovc[b]) ? -INFINITY : acc[k];
    total[(size_t)b*NV_ + v] = o;
  }
}

// ---------------- K7b: sparse copy scores added into total ----------------
__global__ __launch_bounds__(128) void copy_score2_kernel(
    const int* __restrict__ stw, const float* __restrict__ agg,
    const float* __restrict__ cW, const float* __restrict__ attn_out,
    const int* __restrict__ replist, const int* __restrict__ repcnt,
    float* __restrict__ total)
{
  int b=blockIdx.x;
  int cnt=repcnt[b];
  int g=threadIdx.x;
  __shared__ __align__(16) float srow[128];
  __shared__ float sred[2];
  float aog = attn_out[b*H_+g];
  f32x4 w[32];
  const f32x4* wrow=(const f32x4*)(cW + (size_t)g*H_);
  #pragma unroll
  for (int i=0;i<32;i++) w[i]=wrow[i];
  for (int ri=blockIdx.y; ri<cnt; ri+=gridDim.y){
    int l = replist[b*L_+ri];
    srow[g] = agg[((size_t)b*L_+l)*H_+g];
    __syncthreads();
    float acc=0.f;
    #pragma unroll
    for (int i=0;i<32;i++){
      f32x4 e=((const f32x4*)srow)[i]; f32x4 wv=w[i];
      acc += wv.x*e.x + wv.y*e.y + wv.z*e.z + wv.w*e.w;
    }
    float v = tanhf(acc)*aog;
    #pragma unroll
    for (int o=32;o;o>>=1) v += __shfl_down(v,o);
    if ((g&63)==0) sred[g>>6]=v;
    __syncthreads();
    if (g==0){
      int vtok = stw[b*L_+l];
      total[(size_t)b*NV_ + vtok] += sred[0]+sred[1];
    }
    __syncthreads();
  }
}

// ---------------- K10: vocab softmax (chunked partials + fused finalize) ----------------
__global__ __launch_bounds__(256) void vocab_pass1_kernel(
    const float* __restrict__ total, float* __restrict__ pmax, float* __restrict__ psum)
{
  int b=blockIdx.x, j=blockIdx.y, t=threadIdx.x;
  int lo=j*CHUNKP_, hi=min(lo+CHUNKP_, NV_);
  const float* row = total + (size_t)b*NV_;
  __shared__ float sred[4];
  float m=-INFINITY;
  for (int i=lo+t;i<hi;i+=256) m=fmaxf(m,row[i]);
  #pragma unroll
  for (int o=32;o;o>>=1) m=fmaxf(m,__shfl_down(m,o));
  if ((t&63)==0) sred[t>>6]=m;
  __syncthreads();
  m = fmaxf(fmaxf(sred[0],sred[1]),fmaxf(sred[2],sred[3]));
  __syncthreads();
  float s=0.f;
  if (m > -INFINITY){
    for (int i=lo+t;i<hi;i+=256) s += __expf(row[i]-m);
  }
  #pragma unroll
  for (int o=32;o;o>>=1) s += __shfl_down(s,o);
  if ((t&63)==0) sred[t>>6]=s;
  __syncthreads();
  if (t==0){ pmax[b*8+j]=m; psum[b*8+j]=sred[0]+sred[1]+sred[2]+sred[3]; }
}

__global__ __launch_bounds__(256) void vocab_norm_kernel(
    float* __restrict__ total, const float* __restrict__ pmax,
    const float* __restrict__ psum)
{
  int b=blockIdx.x, j=blockIdx.y, t=threadIdx.x;
  // inline final reduce of 8 partials (every thread, registers only)
  float M=-INFINITY;
  #pragma unroll
  for (int k=0;k<8;k++) M=fmaxf(M,pmax[b*8+k]);
  float Z=0.f;
  #pragma unroll
  for (int k=0;k<8;k++){
    float pj=pmax[b*8+k];
    Z += (pj > -INFINITY) ? psum[b*8+k]*__expf(pj-M) : 0.f;
  }
  float rz=1.0f/Z;
  int lo=j*CHUNK_, hi=min(lo+CHUNK_, NV_);
  float* row = total + (size_t)b*NV_;
  for (int i=lo+t;i<hi;i+=256) row[i] = __expf(row[i]-M)*rz;
}

// ---------------- launch ----------------
extern "C" void kernel_launch(void* const* d_in, const int* in_sizes, int n_in,
                              void* d_out, int out_size, void* d_ws, size_t ws_size,
                              hipStream_t stream)
{
  const int*   src_tokens = (const int*)d_in[0];
  const int*   prev_tok   = (const int*)d_in[2];
  const int*   stw        = (const int*)d_in[4];
  const int*   oovc       = (const int*)d_in[5];
  const float* dstate     = (const float*)d_in[6];
  const float* emb        = (const float*)d_in[7];
  const float* enc_Wih    = (const float*)d_in[8];
  const float* enc_Whh    = (const float*)d_in[9];
  const float* enc_b      = (const float*)d_in[10];
  const float* dec_Wih    = (const float*)d_in[11];
  const float* dec_b      = (const float*)d_in[13];
  const float* attn_W     = (const float*)d_in[14];
  const float* out_W      = (const float*)d_in[15];
  const float* out_b      = (const float*)d_in[16];
  const float* copy_W     = (const float*)d_in[17];
  const float* gen_W      = (const float*)d_in[18];

  float* out      = (float*)d_out;
  float* total    = out;                                 // B*NV
  float* enc_out  = out + (size_t)B_*NV_;                // B*L*H
  float* attn_out = enc_out + (size_t)B_*L_*H_;          // B*H

  float* ws     = (float*)d_ws;
  float* xg     = ws;                                    // B*L*G4
  float* agg    = xg + (size_t)B_*L_*G4_;                // B*L*H
  float* pmax   = agg + (size_t)B_*L_*H_;                // 128
  float* psum   = pmax + 128;                            // 128
  int*   replist= (int*)(psum + 128);                    // B*L
  int*   repcnt = replist + B_*L_;                       // 16

  enc_xg_kernel<<<B_*L_/16, 512, 0, stream>>>(src_tokens, emb, enc_Wih, enc_b, xg);
  enc_lstm_kernel<<<B_, 256, 0, stream>>>(xg, enc_Whh, enc_out);
  midagg_kernel<<<32, 512, 0, stream>>>(src_tokens, prev_tok, enc_out, copy_W, dstate,
                                        emb, dec_Wih, dec_b, attn_W, out_W, out_b, attn_out,
                                        stw, agg, replist, repcnt);
  gen_logits_kernel<<<(NV_+63)/64, 256, 0, stream>>>(attn_out, gen_W, oovc, total);
  copy_score2_kernel<<<dim3(B_,32), 128, 0, stream>>>(stw, agg, copy_W, attn_out, replist, repcnt, total);
  vocab_pass1_kernel<<<dim3(B_,8), 256, 0, stream>>>(total, pmax, psum);
  vocab_norm_kernel<<<dim3(B_,32), 256, 0, stream>>>(total, pmax, psum);
}

// Round 7
// 465.164 us; speedup vs baseline: 1.1465x; 1.1465x over previous
//
#include <hip/hip_runtime.h>
#include <math.h>

#define B_   16
#define L_   256
#define V_   50000
#define NV_  50100
#define E_   128
#define H_   128
#define G4_  512
#define CHUNK_  1566   // ceil(50100/32)
#define CHUNKP_ 6263   // ceil(50100/8)

typedef float f32x4 __attribute__((ext_vector_type(4)));
typedef float f32x2 __attribute__((ext_vector_type(2)));

__device__ __forceinline__ float sigm(float x){ return 1.0f/(1.0f+__expf(-x)); }
__device__ __forceinline__ float tanh_fast(float x){
  x = fminf(15.0f, fmaxf(-15.0f, x));
  float t = __expf(2.0f*x);
  return (t-1.0f)/(t+1.0f);
}

// ---------------- K1: encoder xg = emb[tok] @ W_ih^T + b ----------------
__global__ __launch_bounds__(512) void enc_xg_kernel(
    const int* __restrict__ tok, const float* __restrict__ emb,
    const float* __restrict__ Wih, const float* __restrict__ bias,
    float* __restrict__ xg)
{
  __shared__ __align__(16) float sx[16*128];
  int r0 = blockIdx.x*16;
  int t = threadIdx.x;
  for (int i=t; i<16*128; i+=512){
    int r=i>>7, e=i&127;
    sx[i] = emb[(size_t)tok[r0+r]*E_ + e];
  }
  __syncthreads();
  int g = t;
  float acc[16];
  #pragma unroll
  for (int r=0;r<16;r++) acc[r]=0.f;
  const f32x4* wr = (const f32x4*)(Wih + (size_t)g*E_);
  #pragma unroll 2
  for (int i=0;i<32;i++){
    f32x4 w = wr[i];
    #pragma unroll
    for (int r=0;r<16;r++){
      f32x4 x = ((const f32x4*)(sx + r*128))[i];
      acc[r] += w.x*x.x + w.y*x.y + w.z*x.z + w.w*x.w;
    }
  }
  float bg = bias[g];
  #pragma unroll
  for (int r=0;r<16;r++) xg[(size_t)(r0+r)*G4_ + g] = acc[r] + bg;
}

// ---------------- K2: encoder LSTM recurrence ----------------
// 16 blocks, 1024 threads (16 waves, 4/SIMD). Thread t owns HALF a gate
// row: g=t>>1, half=t&1 -> 64 fp32 W values = 64 VGPRs, below the ~84 the
// RA grants freely (R1/R2 evidence). R6 lesson: fp16 accumulate in the
// recurrence loses 4.6e-3 -> all math fp32. Partner halves combine with
// shfl_xor(1) (intra-wave). DS count/CU unchanged vs R4; VALU halves;
// 4 waves/SIMD hides latency.
__global__ __launch_bounds__(1024, 4) void enc_lstm_kernel(
    const float* __restrict__ xg, const float* __restrict__ Whh,
    float* __restrict__ enc_out)
{
  int b = blockIdx.x;
  int t = threadIdx.x;          // 0..1023
  int g = t >> 1;               // gate row 0..511
  int half = t & 1;             // which half of h

  f32x4 w4[16];
  {
    const f32x4* wr = (const f32x4*)(Whh + (size_t)g*H_ + half*64);
    #pragma unroll
    for (int k=0;k<16;k++) w4[k] = wr[k];
  }
  #pragma unroll
  for (int k=0;k<16;k++) asm volatile("" : "+v"(w4[k]));

  __shared__ __align__(16) float sh_h[128];
  __shared__ float sh_g[512];
  if (t<128) sh_h[t]=0.f;
  float c = 0.f;
  const float* xgb = xg + (size_t)b*L_*G4_;
  float* eob = enc_out + (size_t)b*L_*H_;
  __syncthreads();

  const f32x4* hbase = (const f32x4*)(sh_h + half*64);
  bool is_gg = (g>=256 && g<384);   // t in [512,768): waves 8-11, wave-uniform
  float xc = xgb[g];
  float xn = xgb[G4_ + g];

  for (int s=0;s<L_;s++){
    float xm = (s+2<L_) ? xgb[(size_t)(s+2)*G4_ + g] : 0.f;  // prefetch depth 2
    f32x2 a0={half ? 0.f : xc, 0.f}, a1={0.f,0.f}, a2={0.f,0.f}, a3={0.f,0.f};
    #pragma unroll
    for (int k=0;k<16;k+=4){
      f32x4 h0=hbase[k], h1=hbase[k+1], h2=hbase[k+2], h3=hbase[k+3];
      a0 += w4[k+0].xy*h0.xy; a1 += w4[k+0].zw*h0.zw;
      a2 += w4[k+1].xy*h1.xy; a3 += w4[k+1].zw*h1.zw;
      a0 += w4[k+2].xy*h2.xy; a1 += w4[k+2].zw*h2.zw;
      a2 += w4[k+3].xy*h3.xy; a3 += w4[k+3].zw*h3.zw;
    }
    f32x2 as = (a0+a1)+(a2+a3);
    float acc = as.x + as.y;
    acc += __shfl_xor(acc, 1);    // even had xc+dot_lo, odd had dot_hi -> both get full preact
    float act = is_gg ? tanh_fast(acc) : sigm(acc);
    if (!(t&1)) sh_g[g] = act;
    __syncthreads();
    if (t < 128){
      c = sh_g[128+t]*c + sh_g[t]*sh_g[256+t];
      float h = sh_g[384+t]*tanh_fast(c);
      sh_h[t] = h;
      eob[(size_t)s*H_ + t] = h;
    }
    __syncthreads();
    xc = xn; xn = xm;
  }
}

// ---------------- fused: [blocks 0-15] mid chain  /  [blocks 16-31] token agg ----------------
__global__ __launch_bounds__(512) void midagg_kernel(
    const int* __restrict__ src, const int* __restrict__ prev,
    const float* __restrict__ enc_out, const float* __restrict__ cW,
    const float* __restrict__ dstate, const float* __restrict__ emb,
    const float* __restrict__ dWih, const float* __restrict__ db,
    const float* __restrict__ aW, const float* __restrict__ oW,
    const float* __restrict__ ob, float* __restrict__ attn_out,
    const int* __restrict__ stw, float* __restrict__ agg,
    int* __restrict__ replist, int* __restrict__ repcnt)
{
  int t=threadIdx.x;
  if (blockIdx.x >= 16){
    // ======== copy_agg path (first-occurrence aggregation) ========
    int b = blockIdx.x - 16;
    __shared__ int stok[256];
    __shared__ int scnt;
    if (t<256) stok[t] = stw[b*L_+t];
    if (t==0) scnt=0;
    __syncthreads();
    if (t<256){
      int tok = stok[t];
      int first=0;
      while (stok[first]!=tok) first++;
      if (first==t){
        int myidx = atomicAdd(&scnt,1);
        f32x4 acc[32];
        #pragma unroll
        for (int i=0;i<32;i++) acc[i]=(f32x4){0.f,0.f,0.f,0.f};
        for (int l2=t; l2<L_; l2++){
          if (stok[l2]==tok){
            const f32x4* e=(const f32x4*)(enc_out + ((size_t)b*L_+l2)*H_);
            #pragma unroll
            for (int i=0;i<32;i++) acc[i]+=e[i];
          }
        }
        f32x4* dst=(f32x4*)(agg + ((size_t)b*L_+t)*H_);
        #pragma unroll
        for (int i=0;i<32;i++) dst[i]=acc[i];
        replist[b*L_+myidx]=t;
      }
    }
    __syncthreads();
    if (t==0) repcnt[b]=scnt;
    return;
  }

  // ======== mid path: copy scores + copy softmax/state + dec step + attention ========
  int b=blockIdx.x;
  __shared__ float s_scopy[256];
  __shared__ int   mlist[256];
  __shared__ int   mcnt;
  __shared__ __align__(16) float se[128];
  __shared__ float sw[256];
  __shared__ float spart[512];
  __shared__ float sred[4];
  __shared__ __align__(16) float sin_[256];
  __shared__ float sg[512];
  __shared__ __align__(16) float sr[128];
  __shared__ __align__(16) float sq[128];
  __shared__ float sc[256];
  __shared__ __align__(16) float sctx[128];

  if (t==0) mcnt=0;
  __syncthreads();
  if (t<256){
    s_scopy[t]=0.f;
    if (src[b*L_+t]==prev[b]){ int i=atomicAdd(&mcnt,1); mlist[i]=t; }
  }
  __syncthreads();
  for (int mi=0; mi<mcnt; mi++){
    int l = mlist[mi];
    if (t<128) se[t] = enc_out[((size_t)b*L_+l)*H_ + t];
    __syncthreads();
    if (t<128){
      const f32x4* wr = (const f32x4*)(cW + (size_t)t*H_);
      const f32x4* e4 = (const f32x4*)se;
      float acc=0.f;
      #pragma unroll
      for (int i=0;i<32;i++){
        f32x4 wv=wr[i], e=e4[i];
        acc += wv.x*e.x + wv.y*e.y + wv.z*e.z + wv.w*e.w;
      }
      float v = tanhf(acc)*dstate[b*H_+t];
      #pragma unroll
      for (int o=32;o;o>>=1) v += __shfl_down(v,o);
      if ((t&63)==0) sred[t>>6]=v;
    }
    __syncthreads();
    if (t==0) s_scopy[l]=sred[0]+sred[1];
    __syncthreads();
  }

  // softmax over copy scores
  float v = (t<256) ? s_scopy[t] : -INFINITY;
  {
    float m=v;
    #pragma unroll
    for (int o=32;o;o>>=1) m=fmaxf(m,__shfl_down(m,o));
    if (t<256 && (t&63)==0) sred[t>>6]=m;
  }
  __syncthreads();
  float m4 = fmaxf(fmaxf(sred[0],sred[1]),fmaxf(sred[2],sred[3]));
  __syncthreads();
  float e = (t<256) ? __expf(v-m4) : 0.f;
  {
    float z=e;
    #pragma unroll
    for (int o=32;o;o>>=1) z += __shfl_down(z,o);
    if (t<256 && (t&63)==0) sred[t>>6]=z;
  }
  __syncthreads();
  {
    float z4 = sred[0]+sred[1]+sred[2]+sred[3];
    if (t<256) sw[t] = e/z4;
  }
  __syncthreads();

  // copy_state
  {
    int ch=t>>7, h=t&127;
    float acc=0.f;
    const float* eb = enc_out + (size_t)b*L_*H_;
    for (int l=ch*64; l<ch*64+64; l++) acc += sw[l]*eb[(size_t)l*H_+h];
    spart[t]=acc;
  }
  __syncthreads();
  if (t<128){
    float cst = spart[t]+spart[128+t]+spart[256+t]+spart[384+t];
    sin_[128+t]=cst;
    sin_[t]=emb[(size_t)prev[b]*E_+t];
  }
  __syncthreads();

  // decoder single LSTM step (h0=c0=0)
  {
    const f32x4* wr=(const f32x4*)(dWih + (size_t)t*256);
    const f32x4* x4=(const f32x4*)sin_;
    f32x2 d0={db[t],0.f}, d1={0.f,0.f}, d2={0.f,0.f}, d3={0.f,0.f};
    #pragma unroll
    for (int k=0;k<64;k+=4){
      f32x4 xa=x4[k], xb=x4[k+1], xc=x4[k+2], xd=x4[k+3];
      f32x4 wva=wr[k], wvb=wr[k+1], wvc=wr[k+2], wvd=wr[k+3];
      d0 += wva.xy*xa.xy; d1 += wva.zw*xa.zw;
      d2 += wvb.xy*xb.xy; d3 += wvb.zw*xb.zw;
      d0 += wvc.xy*xc.xy; d1 += wvc.zw*xc.zw;
      d2 += wvd.xy*xd.xy; d3 += wvd.zw*xd.zw;
    }
    f32x2 dsm=(d0+d1)+(d2+d3);
    sg[t]=dsm.x+dsm.y;
  }
  __syncthreads();
  if (t<128){
    float iv=sg[t], gv=sg[256+t], ov=sg[384+t];
    float cc = sigm(iv)*tanhf(gv);
    sr[t] = sigm(ov)*tanhf(cc);
  }
  __syncthreads();

  // q = attn_W @ rnn
  if (t<128){
    const f32x4* wr=(const f32x4*)(aW + (size_t)t*H_);
    const f32x4* x4=(const f32x4*)sr;
    float acc=0.f;
    #pragma unroll
    for (int i=0;i<32;i++){
      f32x4 wv=wr[i], x=x4[i];
      acc += wv.x*x.x + wv.y*x.y + wv.z*x.z + wv.w*x.w;
    }
    sq[t]=acc;
  }
  __syncthreads();

  // scores + pad mask
  if (t<256){
    const f32x4* e4=(const f32x4*)(enc_out + ((size_t)b*L_+t)*H_);
    const f32x4* q4=(const f32x4*)sq;
    float acc=0.f;
    #pragma unroll
    for (int i=0;i<32;i++){
      f32x4 ev=e4[i], q=q4[i];
      acc += ev.x*q.x + ev.y*q.y + ev.z*q.z + ev.w*q.w;
    }
    if (src[b*L_+t]==0) acc=-INFINITY;
    sc[t]=acc;
  }
  __syncthreads();

  // attn softmax
  v = (t<256) ? sc[t] : -INFINITY;
  {
    float m=v;
    #pragma unroll
    for (int o=32;o;o>>=1) m=fmaxf(m,__shfl_down(m,o));
    if (t<256 && (t&63)==0) sred[t>>6]=m;
  }
  __syncthreads();
  m4 = fmaxf(fmaxf(sred[0],sred[1]),fmaxf(sred[2],sred[3]));
  __syncthreads();
  e = (t<256) ? __expf(v-m4) : 0.f;
  {
    float z=e;
    #pragma unroll
    for (int o=32;o;o>>=1) z += __shfl_down(z,o);
    if (t<256 && (t&63)==0) sred[t>>6]=z;
  }
  __syncthreads();
  {
    float z4 = sred[0]+sred[1]+sred[2]+sred[3];
    if (t<256) sc[t] = e/z4;
  }
  __syncthreads();

  // ctx
  {
    int ch=t>>7, h=t&127;
    float acc=0.f;
    const float* eb = enc_out + (size_t)b*L_*H_;
    for (int l=ch*64; l<ch*64+64; l++) acc += sc[l]*eb[(size_t)l*H_+h];
    spart[t]=acc;
  }
  __syncthreads();
  if (t<128) sctx[t] = spart[t]+spart[128+t]+spart[256+t]+spart[384+t];
  __syncthreads();

  // attn_out = tanh(out_W @ [rnn,ctx] + out_b)
  if (t<128){
    const f32x4* wr=(const f32x4*)(oW + (size_t)t*256);
    const f32x4* r4=(const f32x4*)sr;
    const f32x4* c4=(const f32x4*)sctx;
    float acc=ob[t];
    #pragma unroll
    for (int i=0;i<32;i++){
      f32x4 wv=wr[i], x=r4[i];
      acc += wv.x*x.x + wv.y*x.y + wv.z*x.z + wv.w*x.w;
    }
    #pragma unroll
    for (int i=0;i<32;i++){
      f32x4 wv=wr[32+i], x=c4[i];
      acc += wv.x*x.x + wv.y*x.y + wv.z*x.z + wv.w*x.w;
    }
    attn_out[b*H_+t]=tanhf(acc);
  }
}

// ---------------- K9: gen logits + masks -> total ----------------
__global__ __launch_bounds__(256) void gen_logits_kernel(
    const float* __restrict__ attn_out, const float* __restrict__ gW,
    const int* __restrict__ oovc, float* __restrict__ total)
{
  __shared__ float sa[B_*H_];
  __shared__ float sw[64*129];
  int t=threadIdx.x;
  int v0=blockIdx.x*64;
  for (int i=t;i<B_*H_;i+=256) sa[i]=attn_out[i];
  for (int i=t;i<64*32;i+=256){
    int r=i>>5, cc=i&31;
    if (v0+r<NV_){
      float4 wv = ((const float4*)(gW + (size_t)(v0+r)*H_))[cc];
      float* dst = sw + r*129 + cc*4;
      dst[0]=wv.x; dst[1]=wv.y; dst[2]=wv.z; dst[3]=wv.w;
    }
  }
  __syncthreads();
  int vl=t&63, bq=t>>6;
  int v=v0+vl;
  if (v>=NV_) return;
  float acc[4]={0.f,0.f,0.f,0.f};
  const float* wrow = sw + vl*129;
  #pragma unroll 8
  for (int h4=0; h4<32; h4++){
    float w0=wrow[h4*4+0], w1=wrow[h4*4+1], w2=wrow[h4*4+2], w3=wrow[h4*4+3];
    #pragma unroll
    for (int k=0;k<4;k++){
      float4 a = ((const float4*)(sa + (bq*4+k)*H_))[h4];
      acc[k] += w0*a.x + w1*a.y + w2*a.z + w3*a.w;
    }
  }
  #pragma unroll
  for (int k=0;k<4;k++){
    int b=bq*4+k;
    float o = (v==1 || v >= V_ + oovc[b]) ? -INFINITY : acc[k];
    total[(size_t)b*NV_ + v] = o;
  }
}

// ---------------- K7b: sparse copy scores added into total ----------------
__global__ __launch_bounds__(128) void copy_score2_kernel(
    const int* __restrict__ stw, const float* __restrict__ agg,
    const float* __restrict__ cW, const float* __restrict__ attn_out,
    const int* __restrict__ replist, const int* __restrict__ repcnt,
    float* __restrict__ total)
{
  int b=blockIdx.x;
  int cnt=repcnt[b];
  int g=threadIdx.x;
  __shared__ __align__(16) float srow[128];
  __shared__ float sred[2];
  float aog = attn_out[b*H_+g];
  f32x4 w[32];
  const f32x4* wrow=(const f32x4*)(cW + (size_t)g*H_);
  #pragma unroll
  for (int i=0;i<32;i++) w[i]=wrow[i];
  for (int ri=blockIdx.y; ri<cnt; ri+=gridDim.y){
    int l = replist[b*L_+ri];
    srow[g] = agg[((size_t)b*L_+l)*H_+g];
    __syncthreads();
    float acc=0.f;
    #pragma unroll
    for (int i=0;i<32;i++){
      f32x4 e=((const f32x4*)srow)[i]; f32x4 wv=w[i];
      acc += wv.x*e.x + wv.y*e.y + wv.z*e.z + wv.w*e.w;
    }
    float v = tanhf(acc)*aog;
    #pragma unroll
    for (int o=32;o;o>>=1) v += __shfl_down(v,o);
    if ((g&63)==0) sred[g>>6]=v;
    __syncthreads();
    if (g==0){
      int vtok = stw[b*L_+l];
      total[(size_t)b*NV_ + vtok] += sred[0]+sred[1];
    }
    __syncthreads();
  }
}

// ---------------- K10: vocab softmax (chunked partials + fused finalize) ----------------
__global__ __launch_bounds__(256) void vocab_pass1_kernel(
    const float* __restrict__ total, float* __restrict__ pmax, float* __restrict__ psum)
{
  int b=blockIdx.x, j=blockIdx.y, t=threadIdx.x;
  int lo=j*CHUNKP_, hi=min(lo+CHUNKP_, NV_);
  const float* row = total + (size_t)b*NV_;
  __shared__ float sred[4];
  float m=-INFINITY;
  for (int i=lo+t;i<hi;i+=256) m=fmaxf(m,row[i]);
  #pragma unroll
  for (int o=32;o;o>>=1) m=fmaxf(m,__shfl_down(m,o));
  if ((t&63)==0) sred[t>>6]=m;
  __syncthreads();
  m = fmaxf(fmaxf(sred[0],sred[1]),fmaxf(sred[2],sred[3]));
  __syncthreads();
  float s=0.f;
  if (m > -INFINITY){
    for (int i=lo+t;i<hi;i+=256) s += __expf(row[i]-m);
  }
  #pragma unroll
  for (int o=32;o;o>>=1) s += __shfl_down(s,o);
  if ((t&63)==0) sred[t>>6]=s;
  __syncthreads();
  if (t==0){ pmax[b*8+j]=m; psum[b*8+j]=sred[0]+sred[1]+sred[2]+sred[3]; }
}

__global__ __launch_bounds__(256) void vocab_norm_kernel(
    float* __restrict__ total, const float* __restrict__ pmax,
    const float* __restrict__ psum)
{
  int b=blockIdx.x, j=blockIdx.y, t=threadIdx.x;
  float M=-INFINITY;
  #pragma unroll
  for (int k=0;k<8;k++) M=fmaxf(M,pmax[b*8+k]);
  float Z=0.f;
  #pragma unroll
  for (int k=0;k<8;k++){
    float pj=pmax[b*8+k];
    Z += (pj > -INFINITY) ? psum[b*8+k]*__expf(pj-M) : 0.f;
  }
  float rz=1.0f/Z;
  int lo=j*CHUNK_, hi=min(lo+CHUNK_, NV_);
  float* row = total + (size_t)b*NV_;
  for (int i=lo+t;i<hi;i+=256) row[i] = __expf(row[i]-M)*rz;
}

// ---------------- launch ----------------
extern "C" void kernel_launch(void* const* d_in, const int* in_sizes, int n_in,
                              void* d_out, int out_size, void* d_ws, size_t ws_size,
                              hipStream_t stream)
{
  const int*   src_tokens = (const int*)d_in[0];
  const int*   prev_tok   = (const int*)d_in[2];
  const int*   stw        = (const int*)d_in[4];
  const int*   oovc       = (const int*)d_in[5];
  const float* dstate     = (const float*)d_in[6];
  const float* emb        = (const float*)d_in[7];
  const float* enc_Wih    = (const float*)d_in[8];
  const float* enc_Whh    = (const float*)d_in[9];
  const float* enc_b      = (const float*)d_in[10];
  const float* dec_Wih    = (const float*)d_in[11];
  const float* dec_b      = (const float*)d_in[13];
  const float* attn_W     = (const float*)d_in[14];
  const float* out_W      = (const float*)d_in[15];
  const float* out_b      = (const float*)d_in[16];
  const float* copy_W     = (const float*)d_in[17];
  const float* gen_W      = (const float*)d_in[18];

  float* out      = (float*)d_out;
  float* total    = out;                                 // B*NV
  float* enc_out  = out + (size_t)B_*NV_;                // B*L*H
  float* attn_out = enc_out + (size_t)B_*L_*H_;          // B*H

  float* ws     = (float*)d_ws;
  float* xg     = ws;                                    // B*L*G4
  float* agg    = xg + (size_t)B_*L_*G4_;                // B*L*H
  float* pmax   = agg + (size_t)B_*L_*H_;                // 128
  float* psum   = pmax + 128;                            // 128
  int*   replist= (int*)(psum + 128);                    // B*L
  int*   repcnt = replist + B_*L_;                       // 16

  enc_xg_kernel<<<B_*L_/16, 512, 0, stream>>>(src_tokens, emb, enc_Wih, enc_b, xg);
  enc_lstm_kernel<<<B_, 1024, 0, stream>>>(xg, enc_Whh, enc_out);
  midagg_kernel<<<32, 512, 0, stream>>>(src_tokens, prev_tok, enc_out, copy_W, dstate,
                                        emb, dec_Wih, dec_b, attn_W, out_W, out_b, attn_out,
                                        stw, agg, replist, repcnt);
  gen_logits_kernel<<<(NV_+63)/64, 256, 0, stream>>>(attn_out, gen_W, oovc, total);
  copy_score2_kernel<<<dim3(B_,32), 128, 0, stream>>>(stw, agg, copy_W, attn_out, replist, repcnt, total);
  vocab_pass1_kernel<<<dim3(B_,8), 256, 0, stream>>>(total, pmax, psum);
  vocab_norm_kernel<<<dim3(B_,32), 256, 0, stream>>>(total, pmax, psum);
}